// Round 1
// baseline (2409.743 us; speedup 1.0000x reference)
//
#include <hip/hip_runtime.h>

// Conv2d 3x3 s1 p1, NCHW fp32: N=32, Cin=128, H=W=56, Cout=256.
// Round 1: correct fp32 direct conv, register-blocked 4 (W) x 4 (Cout)
// outputs per thread. Baseline for later bf16-MFMA implicit GEMM.

constexpr int CIN  = 128;
constexpr int Hc   = 56;
constexpr int Wc   = 56;
constexpr int COUT = 256;

__global__ __launch_bounds__(256) void conv_k(
    const float* __restrict__ x,     // [N][CIN][H][W]
    const float* __restrict__ wgt,   // [COUT][CIN][3][3]
    const float* __restrict__ bias,  // [COUT]
    float* __restrict__ out)         // [N][COUT][H][W]
{
    int idx = blockIdx.x * 256 + threadIdx.x;
    // decompose: wg (14 groups of 4 along W) fastest -> coalesced x/out access
    int wg  = idx % 14;
    int t   = idx / 14;
    int ho  = t % 56;  t /= 56;
    int cog = t % 64;
    int n   = t / 64;
    int w0  = wg * 4;
    int co0 = cog * 4;

    float acc[4][4];  // [co][pixel]
#pragma unroll
    for (int j = 0; j < 4; ++j) {
        float bj = bias[co0 + j];
#pragma unroll
        for (int p = 0; p < 4; ++p) acc[j][p] = bj;
    }

    const float* xn = x + (size_t)n * CIN * Hc * Wc;

    for (int ci = 0; ci < CIN; ++ci) {
        // load 3 rows x 6 cols of x (zero-padded at edges)
        float xr[3][6];
#pragma unroll
        for (int kh = 0; kh < 3; ++kh) {
            int hi = ho + kh - 1;
            if (hi >= 0 && hi < Hc) {
                const float* row = xn + ((size_t)ci * Hc + hi) * Wc;
                float4 c = *reinterpret_cast<const float4*>(row + w0);  // 16B-aligned: W*4=224, w0*4 mult of 16
                xr[kh][1] = c.x; xr[kh][2] = c.y; xr[kh][3] = c.z; xr[kh][4] = c.w;
                xr[kh][0] = (w0 > 0)      ? row[w0 - 1] : 0.0f;
                xr[kh][5] = (w0 + 4 < Wc) ? row[w0 + 4] : 0.0f;
            } else {
#pragma unroll
                for (int q = 0; q < 6; ++q) xr[kh][q] = 0.0f;
            }
        }
        // 4 output channels, 9 taps each, 4 pixels
#pragma unroll
        for (int j = 0; j < 4; ++j) {
            const float* wp = wgt + ((size_t)(co0 + j) * CIN + ci) * 9;
            float wv[9];
#pragma unroll
            for (int q = 0; q < 9; ++q) wv[q] = wp[q];
#pragma unroll
            for (int kh = 0; kh < 3; ++kh)
#pragma unroll
                for (int kw = 0; kw < 3; ++kw)
#pragma unroll
                    for (int p = 0; p < 4; ++p)
                        acc[j][p] = fmaf(xr[kh][p + kw], wv[kh * 3 + kw], acc[j][p]);
        }
    }

#pragma unroll
    for (int j = 0; j < 4; ++j) {
        float4 v = make_float4(acc[j][0], acc[j][1], acc[j][2], acc[j][3]);
        *reinterpret_cast<float4*>(
            out + (((size_t)n * COUT + co0 + j) * Hc + ho) * Wc + w0) = v;
    }
}

extern "C" void kernel_launch(void* const* d_in, const int* in_sizes, int n_in,
                              void* d_out, int out_size, void* d_ws, size_t ws_size,
                              hipStream_t stream) {
    const float* x   = (const float*)d_in[0];
    const float* w   = (const float*)d_in[1];
    const float* b   = (const float*)d_in[2];
    float* out       = (float*)d_out;

    // total threads = 32 * 64 * 56 * 14 = 1,605,632 -> 6272 blocks of 256 (exact)
    dim3 grid(6272), block(256);
    hipLaunchKernelGGL(conv_k, grid, block, 0, stream, x, w, b, out);
}

// Round 2
// 104.574 us; speedup vs baseline: 23.0435x; 23.0435x over previous
//
#include <hip/hip_runtime.h>

// Conv2d 3x3 s1 p1 NCHW fp32: N=32, Cin=128, H=W=56, Cout=256.
// Round 2: bf16 MFMA implicit GEMM (m97 structure).
//   ws layout: [xT: NHWC bf16 25.7MB][wT: [tap][co][ci] bf16 0.59MB][zeropage 128B]
//   GEMM: C[co][m] = sum_k W[co][k] * im2col[k][m], tile 128(co) x 128(m), BK=64.
//   global_load_lds w=16 staging, source pre-swizzled (chunk ^= row&7) so
//   ds_read_b128 fragment reads are conflict-free. C layout col=lane&15=m ->
//   coalesced 64B output stores.

typedef __attribute__((ext_vector_type(8))) short short8;
typedef __attribute__((ext_vector_type(4))) float float4v;

constexpr int NB = 32, CI = 128, HH = 56, WW = 56, CO = 256;
constexpr int HWP = HH * WW;            // 3136
constexpr int M_TOTAL = NB * HWP;       // 100352
constexpr size_t XT_BYTES = (size_t)NB * HWP * CI * 2;      // 25,690,112
constexpr size_t WT_BYTES = (size_t)9 * CO * CI * 2;        // 589,824
constexpr size_t ZP_OFF   = XT_BYTES + WT_BYTES;            // 26,279,936
constexpr size_t WS_NEED  = ZP_OFF + 128;

__device__ inline ushort f2bf(float v) {
    union { float f; uint u; } c; c.f = v;
    uint u = c.u;
    return (ushort)((u + 0x7fffu + ((u >> 16) & 1u)) >> 16);
}

// ---- x: [n][ci][h][w] f32  ->  xT: [n][h][w][ci] bf16 (tiled transpose) ----
__global__ __launch_bounds__(256) void xform_x(const float* __restrict__ x,
                                               ushort* __restrict__ xT) {
    int b = blockIdx.x;
    int cit = b & 3;            // 4 ci-tiles of 32
    int hwt = (b >> 2) % 49;    // 49 hw-tiles of 64
    int n   = b / (4 * 49);
    int ci0 = cit * 32, hw0 = hwt * 64;
    __shared__ float t[32][65];
    int tx = threadIdx.x;
    int col = tx & 63, r4 = tx >> 6;
#pragma unroll
    for (int rr = 0; rr < 8; ++rr) {
        int row = rr * 4 + r4;  // ci-local
        t[row][col] = x[((size_t)n * CI + ci0 + row) * HWP + hw0 + col];
    }
    __syncthreads();
    int i = tx & 31, j0 = tx >> 5;
#pragma unroll
    for (int jj = 0; jj < 8; ++jj) {
        int j = jj * 8 + j0;    // hw-local
        xT[((size_t)n * HWP + hw0 + j) * CI + ci0 + i] = f2bf(t[i][j]);
    }
}

// ---- w: [co][ci][kh][kw] f32 -> wT: [tap][co][ci] bf16 ----
__global__ __launch_bounds__(256) void xform_w(const float* __restrict__ w,
                                               ushort* __restrict__ wT) {
    int o = blockIdx.x * 256 + threadIdx.x;  // 294912 total
    int ci = o & 127;
    int co = (o >> 7) & 255;
    int tap = o >> 15;
    wT[o] = f2bf(w[((size_t)co * CI + ci) * 9 + tap]);
}

// ---- main implicit GEMM ----
__global__ __launch_bounds__(256) void gemm_conv(
    const ushort* __restrict__ xT, const ushort* __restrict__ wT,
    const ushort* __restrict__ zp, const float* __restrict__ bias,
    float* __restrict__ out)
{
    __shared__ ushort As[128 * 64];  // weights tile [co][ci], swizzled, 16KB
    __shared__ ushort Bs[128 * 64];  // im2col tile  [m][ci],  swizzled, 16KB

    const int mblk = blockIdx.x >> 1;   // 784 m-blocks
    const int cblk = blockIdx.x & 1;    // 2 co-blocks (fast -> share xT in L2)
    const int tid = threadIdx.x, lane = tid & 63, wv = tid >> 6;
    const int wco = wv >> 1, wm = wv & 1;              // 2x2 wave grid
    const int s = (lane & 7) ^ ((lane >> 3) & 7);      // pre-swizzled src chunk

    // staging rows: 4 per thread (8 rows per wave-instr)
    int ho_[4], wo_[4], mpix[4], rowW[4];
#pragma unroll
    for (int q = 0; q < 4; ++q) {
        int r = wv * 32 + q * 8 + (lane >> 3);
        rowW[q] = r;
        int m = mblk * 128 + r;
        mpix[q] = m;
        int hw = m % HWP;
        ho_[q] = hw / WW;
        wo_[q] = hw % WW;
    }

    float4v acc[4][4];
#pragma unroll
    for (int i = 0; i < 4; ++i)
#pragma unroll
        for (int j = 0; j < 4; ++j) acc[i][j] = (float4v)(0.0f);

    for (int tap = 0; tap < 9; ++tap) {
        const int dh = tap / 3 - 1, dw = tap % 3 - 1;
        for (int cb = 0; cb < 2; ++cb) {
            // stage weights tile (16KB): 4 x global_load_lds(16B) per thread
#pragma unroll
            for (int q = 0; q < 4; ++q) {
                const ushort* g = wT + ((size_t)tap * CO + cblk * 128 + rowW[q]) * CI
                                     + cb * 64 + s * 8;
                __builtin_amdgcn_global_load_lds(
                    (const __attribute__((address_space(1))) uint*)g,
                    (__attribute__((address_space(3))) uint*)(As + (wv * 32 + q * 8) * 64),
                    16, 0, 0);
            }
            // stage im2col tile (16KB), OOB rows -> zero page
#pragma unroll
            for (int q = 0; q < 4; ++q) {
                int hi = ho_[q] + dh, wi = wo_[q] + dw;
                bool ok = (hi >= 0) & (hi < HH) & (wi >= 0) & (wi < WW);
                const ushort* g = ok
                    ? (xT + ((size_t)(mpix[q] + dh * WW + dw)) * CI + cb * 64 + s * 8)
                    : (zp + (lane & 7) * 8);
                __builtin_amdgcn_global_load_lds(
                    (const __attribute__((address_space(1))) uint*)g,
                    (__attribute__((address_space(3))) uint*)(Bs + (wv * 32 + q * 8) * 64),
                    16, 0, 0);
            }
            __syncthreads();   // compiler emits vmcnt(0) drain before barrier
            // compute: 2 k-halves x (4 co-frag x 4 m-frag) MFMAs
#pragma unroll
            for (int kk = 0; kk < 2; ++kk) {
                short8 a[4], b[4];
#pragma unroll
                for (int f = 0; f < 4; ++f) {
                    int row = wco * 64 + f * 16 + (lane & 15);
                    int ch = (kk * 4 + (lane >> 4)) ^ (row & 7);
                    a[f] = *(const short8*)(As + row * 64 + ch * 8);
                }
#pragma unroll
                for (int f = 0; f < 4; ++f) {
                    int row = wm * 64 + f * 16 + (lane & 15);
                    int ch = (kk * 4 + (lane >> 4)) ^ (row & 7);
                    b[f] = *(const short8*)(Bs + row * 64 + ch * 8);
                }
#pragma unroll
                for (int i = 0; i < 4; ++i)
#pragma unroll
                    for (int j = 0; j < 4; ++j)
                        acc[i][j] = __builtin_amdgcn_mfma_f32_16x16x32_bf16(
                            a[i], b[j], acc[i][j], 0, 0, 0);
            }
            __syncthreads();
        }
    }

    // epilogue: C[co][m] + bias[co] -> out[n][co][h][w]
    const int co0 = cblk * 128 + wco * 64;
    const int m0  = mblk * 128 + wm * 64;
    float bv[4][4];
#pragma unroll
    for (int i = 0; i < 4; ++i)
#pragma unroll
        for (int r = 0; r < 4; ++r)
            bv[i][r] = bias[co0 + i * 16 + (lane >> 4) * 4 + r];
#pragma unroll
    for (int j = 0; j < 4; ++j) {
        int m = m0 + j * 16 + (lane & 15);
        int n = m / HWP, hw = m % HWP;
        float* obase = out + (size_t)n * CO * HWP + hw;
#pragma unroll
        for (int i = 0; i < 4; ++i) {
            int co = co0 + i * 16 + (lane >> 4) * 4;
#pragma unroll
            for (int r = 0; r < 4; ++r)
                obase[(size_t)(co + r) * HWP] = acc[i][j][r] + bv[i][r];
        }
    }
}

// ---- fallback (round-1 direct conv) if ws too small ----
__global__ __launch_bounds__(256) void conv_k(
    const float* __restrict__ x, const float* __restrict__ wgt,
    const float* __restrict__ bias, float* __restrict__ out)
{
    int idx = blockIdx.x * 256 + threadIdx.x;
    int wg = idx % 14; int t = idx / 14;
    int ho = t % 56; t /= 56;
    int cog = t % 64; int n = t / 64;
    int w0 = wg * 4, co0 = cog * 4;
    float acc[4][4];
#pragma unroll
    for (int j = 0; j < 4; ++j) {
        float bj = bias[co0 + j];
#pragma unroll
        for (int p = 0; p < 4; ++p) acc[j][p] = bj;
    }
    const float* xn = x + (size_t)n * CI * HWP;
    for (int ci = 0; ci < CI; ++ci) {
        float xr[3][6];
#pragma unroll
        for (int kh = 0; kh < 3; ++kh) {
            int hi = ho + kh - 1;
            if (hi >= 0 && hi < HH) {
                const float* row = xn + ((size_t)ci * HH + hi) * WW;
                float4 c = *reinterpret_cast<const float4*>(row + w0);
                xr[kh][1] = c.x; xr[kh][2] = c.y; xr[kh][3] = c.z; xr[kh][4] = c.w;
                xr[kh][0] = (w0 > 0) ? row[w0 - 1] : 0.0f;
                xr[kh][5] = (w0 + 4 < WW) ? row[w0 + 4] : 0.0f;
            } else {
#pragma unroll
                for (int q = 0; q < 6; ++q) xr[kh][q] = 0.0f;
            }
        }
#pragma unroll
        for (int j = 0; j < 4; ++j) {
            const float* wp = wgt + ((size_t)(co0 + j) * CI + ci) * 9;
            float wvv[9];
#pragma unroll
            for (int q = 0; q < 9; ++q) wvv[q] = wp[q];
#pragma unroll
            for (int kh = 0; kh < 3; ++kh)
#pragma unroll
                for (int kw = 0; kw < 3; ++kw)
#pragma unroll
                    for (int p = 0; p < 4; ++p)
                        acc[j][p] = fmaf(xr[kh][p + kw], wvv[kh * 3 + kw], acc[j][p]);
        }
    }
#pragma unroll
    for (int j = 0; j < 4; ++j) {
        float4 v = make_float4(acc[j][0], acc[j][1], acc[j][2], acc[j][3]);
        *reinterpret_cast<float4*>(out + (((size_t)n * CO + co0 + j) * HH + ho) * WW + w0) = v;
    }
}

extern "C" void kernel_launch(void* const* d_in, const int* in_sizes, int n_in,
                              void* d_out, int out_size, void* d_ws, size_t ws_size,
                              hipStream_t stream) {
    const float* x = (const float*)d_in[0];
    const float* w = (const float*)d_in[1];
    const float* b = (const float*)d_in[2];
    float* out = (float*)d_out;

    if (ws_size < WS_NEED) {  // safety fallback
        hipLaunchKernelGGL(conv_k, dim3(6272), dim3(256), 0, stream, x, w, b, out);
        return;
    }

    ushort* xT = (ushort*)d_ws;
    ushort* wT = (ushort*)((char*)d_ws + XT_BYTES);
    ushort* zp = (ushort*)((char*)d_ws + ZP_OFF);

    hipMemsetAsync(zp, 0, 128, stream);
    hipLaunchKernelGGL(xform_x, dim3(32 * 49 * 4), dim3(256), 0, stream, x, xT);
    hipLaunchKernelGGL(xform_w, dim3(9 * CO * CI / 256), dim3(256), 0, stream, w, wT);
    hipLaunchKernelGGL(gemm_conv, dim3(784 * 2), dim3(256), 0, stream,
                       xT, wT, zp, b, out);
}